// Round 4
// baseline (5899.236 us; speedup 1.0000x reference)
//
#include <hip/hip_runtime.h>
#include <math.h>
#include <stdint.h>

#define BB     64
#define TENC   100
#define TDEC   50
#define LDIM   512
#define EE     512
#define HDIM   512
#define FIVEL  2560
#define RSTEPS 8
#define VOUT   30000

typedef __attribute__((ext_vector_type(8))) short short8v;   // 8 x bf16
typedef __attribute__((ext_vector_type(4))) float floatx4;
typedef unsigned short ushort_t;

// ---------------- workspace offsets (float units) ----------------
// Region A (13,107,200 fl): enc_pre_b -> rev_proj_all -> logit_WT + dec_h_b
static const size_t OFF_A        = 0;
static const size_t OFF_WIT_ENC  = 8192000;   // in A, prep only
static const size_t OFF_ENCX     = 8847360;   // in A, prep only (ends 10,485,760)
static const size_t OFF_LOGWT    = 0;         // in A, post-review
static const size_t OFF_DECH     = 7680000;   // in A, decode (ends 8,499,200)
static const size_t OFF_ENC_HS   = 13107200;
static const size_t OFF_ENC_WHT  = 14745600;
static const size_t OFF_REVWC    = 15400960;
static const size_t OFF_DECWC    = 25886720;
static const size_t OFF_REVWT    = 27852800;
static const size_t OFF_DECWT    = 28901376;
static const size_t OFF_REVWH2AT = 29032448;
static const size_t OFF_DECWH2AT = 30081024;
static const size_t OFF_DECX     = 30212096;
static const size_t OFF_THOUGHT  = 31031296;
static const size_t OFF_TPROJ    = 31162368;
static const size_t OFF_HB0      = 31293440;
static const size_t OFF_HB1      = 31309824;
static const size_t OFF_ATTV     = 31326208;
static const size_t OFF_CENC     = 31342592;
static const size_t OFF_BAR      = 31375360;
static const size_t WS_TOTAL     = 31375376;

__device__ __forceinline__ float sigmoidf_(float x) { return 1.0f / (1.0f + __expf(-x)); }
__device__ __forceinline__ float tanh_fast(float x) { return 1.0f - 2.0f / (__expf(2.0f * x) + 1.0f); }
__device__ __forceinline__ unsigned short f2bf(float x) {
    unsigned u = __float_as_uint(x);
    u += 0x7FFFu + ((u >> 16) & 1u);
    return (unsigned short)(u >> 16);
}
__device__ __forceinline__ float bf2f(unsigned short h) {
    return __uint_as_float(((unsigned)h) << 16);
}

// ---------------------------------------------------------------------------
// Device-scope grid barrier. bar[0]=count (must be 0 at kernel entry; returns
// to 0 after each use), bar[1]=generation (monotonic, wrap-safe unsigned).
// ---------------------------------------------------------------------------
__device__ __forceinline__ void gbar(unsigned int* bar, int nblk)
{
    __threadfence();            // release this block's writes (agent scope)
    __syncthreads();
    if (threadIdx.x == 0) {
        unsigned int g = __hip_atomic_load(&bar[1], __ATOMIC_RELAXED, __HIP_MEMORY_SCOPE_AGENT);
        unsigned int v = __hip_atomic_fetch_add(&bar[0], 1u, __ATOMIC_ACQ_REL, __HIP_MEMORY_SCOPE_AGENT);
        if (v == (unsigned int)(nblk - 1)) {
            __hip_atomic_store(&bar[0], 0u, __ATOMIC_RELAXED, __HIP_MEMORY_SCOPE_AGENT);
            __hip_atomic_fetch_add(&bar[1], 1u, __ATOMIC_RELEASE, __HIP_MEMORY_SCOPE_AGENT);
        } else {
            while (__hip_atomic_load(&bar[1], __ATOMIC_RELAXED, __HIP_MEMORY_SCOPE_AGENT) == g)
                __builtin_amdgcn_s_sleep(2);
        }
    }
    __syncthreads();
    __threadfence();            // acquire (invalidate caches so remote writes visible)
}

// ---------------------------------------------------------------------------
// Gather embedding rows -> bf16 matrix X[m][E], m = t*BB + b.
// ---------------------------------------------------------------------------
__global__ __launch_bounds__(128)
void gather_embed(const float* __restrict__ embed, const int* __restrict__ tok,
                  int T, ushort_t* __restrict__ X)
{
    int m = blockIdx.x, t = m / BB, b = m % BB;
    const float* src = embed + (size_t)tok[b * T + t] * EE;
    float4 v = *(const float4*)(src + threadIdx.x * 4);
    ushort4 o = { f2bf(v.x), f2bf(v.y), f2bf(v.z), f2bf(v.w) };
    *(ushort4*)(X + (size_t)m * EE + threadIdx.x * 4) = o;
}

// ---------------------------------------------------------------------------
// WT[z][n][kofs+k] = bf16(W[z][k][n]).  W rows K=gridDim.y*32, cols N.
// ---------------------------------------------------------------------------
__global__ __launch_bounds__(256)
void conv_transpose(const float* __restrict__ W, ushort_t* __restrict__ WT,
                    int N, int ldWT, int kofs, long Wz, long WTz)
{
    W  += (size_t)blockIdx.z * Wz;
    WT += (size_t)blockIdx.z * WTz;
    __shared__ float tile[32][33];
    int n0 = blockIdx.x * 32, k0 = blockIdx.y * 32;
    int tx = threadIdx.x & 31, ty = threadIdx.x >> 5;
    #pragma unroll
    for (int i = 0; i < 4; ++i) {
        int k = k0 + ty + i * 8, n = n0 + tx;
        tile[ty + i * 8][tx] = (n < N) ? W[(size_t)k * N + n] : 0.f;
    }
    __syncthreads();
    #pragma unroll
    for (int i = 0; i < 4; ++i) {
        int n = n0 + ty + i * 8, k = k0 + tx;
        if (n < N) WT[(size_t)n * ldWT + kofs + k] = f2bf(tile[tx][ty + i * 8]);
    }
}

// ---------------------------------------------------------------------------
// bf16 MFMA GEMM (R2/R3-proven): C[m][n] = sum_k A[m][k]*BT[n][k] + bias[n]
// ---------------------------------------------------------------------------
__global__ __launch_bounds__(256)
void gemm_bf16(const ushort_t* __restrict__ A, const ushort_t* __restrict__ BT,
               const float* __restrict__ bias, float* __restrict__ C,
               ushort_t* __restrict__ Cb, int N, int K, long ldc, int remap)
{
    __shared__ ushort_t lds[2][128][32];
    const int tid  = threadIdx.x;
    const int wave = tid >> 6, lane = tid & 63;
    const int m0 = blockIdx.y * 128, n0 = blockIdx.x * 128;
    const int wr = wave >> 1, wc = wave & 1;

    floatx4 acc[4][4] = {};
    const int sr  = lane >> 2;
    const int scp = lane & 3;

    for (int k0 = 0; k0 < K; k0 += 32) {
        #pragma unroll
        for (int half = 0; half < 2; ++half) {
            int rbase = wave * 32 + half * 16;
            int r = rbase + sr;
            int c = scp ^ ((r >> 1) & 3);
            const ushort_t* ga = A + (size_t)(m0 + r) * K + k0 + c * 8;
            int nr = n0 + r; if (nr >= N) nr = 0;
            const ushort_t* gb = BT + (size_t)nr * K + k0 + c * 8;
            __builtin_amdgcn_global_load_lds(
                (const __attribute__((address_space(1))) void*)ga,
                (__attribute__((address_space(3))) void*)&lds[0][rbase][0], 16, 0, 0);
            __builtin_amdgcn_global_load_lds(
                (const __attribute__((address_space(1))) void*)gb,
                (__attribute__((address_space(3))) void*)&lds[1][rbase][0], 16, 0, 0);
        }
        __syncthreads();

        short8v af[4], bv[4];
        #pragma unroll
        for (int i = 0; i < 4; ++i) {
            int ra = wr * 64 + i * 16 + (lane & 15);
            int ca = (lane >> 4) ^ ((ra >> 1) & 3);
            af[i] = *(const short8v*)&lds[0][ra][ca * 8];
            int rb = wc * 64 + i * 16 + (lane & 15);
            int cb = (lane >> 4) ^ ((rb >> 1) & 3);
            bv[i] = *(const short8v*)&lds[1][rb][cb * 8];
        }
        #pragma unroll
        for (int i = 0; i < 4; ++i)
            #pragma unroll
            for (int j = 0; j < 4; ++j)
                acc[i][j] = __builtin_amdgcn_mfma_f32_16x16x32_bf16(af[i], bv[j], acc[i][j], 0, 0, 0);
        __syncthreads();
    }

    const int crow0 = m0 + wr * 64 + (lane >> 4) * 4;
    const int ccol0 = n0 + wc * 64 + (lane & 15);
    #pragma unroll
    for (int i = 0; i < 4; ++i) {
        #pragma unroll
        for (int j = 0; j < 4; ++j) {
            int col = ccol0 + j * 16;
            if (col < N) {
                float bval = bias ? bias[col] : 0.f;
                #pragma unroll
                for (int rr = 0; rr < 4; ++rr) {
                    int m = crow0 + i * 16 + rr;
                    long orow = m;
                    if (remap) { int t = m >> 6, b = m & 63; orow = (long)b * TDEC + t; }
                    float v = acc[i][j][rr] + bval;
                    if (Cb) Cb[orow * ldc + col] = f2bf(v);
                    else    C [orow * ldc + col] = v;
                }
            }
        }
    }
}

// ---------------------------------------------------------------------------
// LSTM accumulation over one 512-wide K segment (R3-proven core).
// Block covers cols c0..c0+15, all 5 gates, M=64 rows. acc[5] persists.
// ---------------------------------------------------------------------------
__device__ __forceinline__ void lstm_accum(
    const ushort_t* __restrict__ Aseg,     // [64][512] bf16
    const ushort_t* __restrict__ BT,       // [2560][ldBT] bf16 (gate-major rows)
    const int ldBT, const int segk, const int c0, floatx4* acc,
    ushort_t (*Alds)[128], ushort_t (*Blds)[128])
{
    const int tid = threadIdx.x;
    const int wave = tid >> 6, lane = tid & 63;
    short8v ra[4], rb[5];
    const ushort_t* ap[4]; ushort_t* aw[4];
    const ushort_t* bp[5]; ushort_t* bw[5];
    #pragma unroll
    for (int j = 0; j < 4; ++j) {
        int idx = tid + j * 256, r = idx >> 4, ch = idx & 15;
        ap[j] = Aseg + (size_t)r * 512 + ch * 8;
        aw[j] = &Alds[r][(ch ^ (r & 7)) * 8];
    }
    #pragma unroll
    for (int j = 0; j < 5; ++j) {
        int idx = tid + j * 256, r = idx >> 4, ch = idx & 15;
        int grow = (r >> 4) * 512 + c0 + (r & 15);
        bp[j] = BT + (size_t)grow * ldBT + segk + ch * 8;
        bw[j] = &Blds[r][(ch ^ (r & 7)) * 8];
    }
    #pragma unroll
    for (int j = 0; j < 4; ++j) ra[j] = *(const short8v*)ap[j];
    #pragma unroll
    for (int j = 0; j < 5; ++j) rb[j] = *(const short8v*)bp[j];

    #pragma unroll 1
    for (int ot = 0; ot < 4; ++ot) {
        __syncthreads();
        #pragma unroll
        for (int j = 0; j < 4; ++j) *(short8v*)aw[j] = ra[j];
        #pragma unroll
        for (int j = 0; j < 5; ++j) *(short8v*)bw[j] = rb[j];
        __syncthreads();
        if (ot < 3) {
            #pragma unroll
            for (int j = 0; j < 4; ++j) ra[j] = *(const short8v*)(ap[j] + (ot + 1) * 128);
            #pragma unroll
            for (int j = 0; j < 5; ++j) rb[j] = *(const short8v*)(bp[j] + (ot + 1) * 128);
        }
        const int arow = wave * 16 + (lane & 15);
        const int q = lane >> 4;
        #pragma unroll
        for (int kk = 0; kk < 4; ++kk) {
            int ch = kk * 4 + q;
            short8v af = *(const short8v*)&Alds[arow][(ch ^ (arow & 7)) * 8];
            #pragma unroll
            for (int g = 0; g < 5; ++g) {
                int brow = g * 16 + (lane & 15);
                short8v bf = *(const short8v*)&Blds[brow][(ch ^ (brow & 7)) * 8];
                acc[g] = __builtin_amdgcn_mfma_f32_16x16x32_bf16(af, bf, acc[g], 0, 0, 0);
            }
        }
    }
}

// Maxout-LSTM epilogue; c carried in creg[4] (block-local columns).
__device__ __forceinline__ void lstm_epilogue(
    floatx4* acc, const float* b0, const float* b1, const float* b2,
    const ushort_t* pre, float* creg, float* c_store,
    ushort_t* h_out, ushort_t* h_copy, int c0)
{
    const int tid = threadIdx.x, wave = tid >> 6, lane = tid & 63;
    const int m = wave * 16 + (lane >> 4) * 4;
    const int c = c0 + (lane & 15);
    float bias[5];
    #pragma unroll
    for (int g = 0; g < 5; ++g) {
        float v = b0[g * 512 + c];
        if (b1) v += b1[g * 512 + c];
        if (b2) v += b2[g * 512 + c];
        bias[g] = v;
    }
    #pragma unroll
    for (int rr = 0; rr < 4; ++rr) {
        int row = m + rr;
        float s[5];
        #pragma unroll
        for (int g = 0; g < 5; ++g) {
            s[g] = acc[g][rr] + bias[g];
            if (pre) s[g] += bf2f(pre[(size_t)row * FIVEL + g * 512 + c]);
        }
        float ig = sigmoidf_(s[0]), fg = sigmoidf_(s[1]), og = sigmoidf_(s[2]);
        float tt = fmaxf(s[3], s[4]);
        float c2 = fg * creg[rr] + ig * tt;
        float h2 = og * tanh_fast(c2);
        creg[rr] = c2;
        ushort_t hb_ = f2bf(h2);
        h_out[(size_t)row * 512 + c] = hb_;
        if (h_copy) h_copy[(size_t)row * 512 + c] = hb_;
        if (c_store) c_store[(size_t)row * 512 + c] = c2;
    }
}

// ---------------------------------------------------------------------------
// Fused hproj + attention for 2 batches (one block). All in one phase.
// hproj[b,n] = bh2a[n] + sum_k h[b,k]*W2aT[n,k]; e = sum tanh(proj+hp)*Watt;
// softmax; attv[b] = sum_a alpha*feats[a,b,:]  (bf16 out).
// ---------------------------------------------------------------------------
struct AttSm {
    ushort_t hl[2][512];
    float hp[2][512];
    float wa[512];
    float ealpha[2][128];
};

__device__ void attend_fused(const ushort_t* __restrict__ hprev,
    const ushort_t* __restrict__ projBase, long projLd,
    const ushort_t* __restrict__ feats,
    const ushort_t* __restrict__ W2aT, const float* __restrict__ b2a,
    const float* __restrict__ Watt, ushort_t* __restrict__ attv,
    int A, int b0, char* smraw)
{
    AttSm* sm = (AttSm*)smraw;
    const int tid = threadIdx.x;
    {
        int i4 = tid * 4;
        int bi = i4 >> 9, k = i4 & 511;
        *(ushort4*)&sm->hl[bi][k] = *(const ushort4*)(hprev + (size_t)(b0 + bi) * 512 + k);
        sm->wa[tid] = Watt[tid];
        sm->wa[tid + 256] = Watt[tid + 256];
    }
    __syncthreads();
    #pragma unroll
    for (int half = 0; half < 2; ++half) {
        int n = tid + half * 256;
        float a0 = b2a[n], a1 = a0;
        const ushort_t* wrow = W2aT + (size_t)n * 512;
        #pragma unroll 4
        for (int k8 = 0; k8 < 64; ++k8) {
            short8v w  = *(const short8v*)(wrow + k8 * 8);
            short8v h0 = *(const short8v*)&sm->hl[0][k8 * 8];
            short8v h1 = *(const short8v*)&sm->hl[1][k8 * 8];
            #pragma unroll
            for (int e = 0; e < 8; ++e) {
                float wf = bf2f((ushort_t)w[e]);
                a0 += wf * bf2f((ushort_t)h0[e]);
                a1 += wf * bf2f((ushort_t)h1[e]);
            }
        }
        sm->hp[0][n] = a0;
        sm->hp[1][n] = a1;
    }
    __syncthreads();
    const int wave = tid >> 6, lane = tid & 63;
    for (int idx = wave; idx < 2 * A; idx += 4) {
        int a = idx >> 1, bi = idx & 1;
        short8v pv = *(const short8v*)(projBase + ((size_t)a * 64 + b0 + bi) * projLd + lane * 8);
        float e = 0.f;
        #pragma unroll
        for (int j = 0; j < 8; ++j) {
            int h = lane * 8 + j;
            e += tanh_fast(bf2f((ushort_t)pv[j]) + sm->hp[bi][h]) * sm->wa[h];
        }
        #pragma unroll
        for (int off = 32; off; off >>= 1) e += __shfl_xor(e, off);
        if (lane == 0) sm->ealpha[bi][a] = e;
    }
    __syncthreads();
    if (wave < 2) {
        int bi = wave;
        float v1 = (lane < A) ? sm->ealpha[bi][lane] : -3.0e38f;
        float v2 = (lane + 64 < A) ? sm->ealpha[bi][lane + 64] : -3.0e38f;
        float mm = fmaxf(v1, v2);
        #pragma unroll
        for (int off = 32; off; off >>= 1) mm = fmaxf(mm, __shfl_xor(mm, off));
        float x1 = (lane < A) ? __expf(v1 - mm) : 0.f;
        float x2 = (lane + 64 < A) ? __expf(v2 - mm) : 0.f;
        float ss = x1 + x2;
        #pragma unroll
        for (int off = 32; off; off >>= 1) ss += __shfl_xor(ss, off);
        float inv = 1.f / ss;
        if (lane < A) sm->ealpha[bi][lane] = x1 * inv;
        if (lane + 64 < A) sm->ealpha[bi][lane + 64] = x2 * inv;
    }
    __syncthreads();
    #pragma unroll
    for (int bi = 0; bi < 2; ++bi) {
        int b = b0 + bi;
        float s0 = 0.f, s1 = 0.f;
        for (int a = 0; a < A; ++a) {
            float al = sm->ealpha[bi][a];
            unsigned int u = *(const unsigned int*)(feats + ((size_t)a * 64 + b) * 512 + tid * 2);
            s0 += al * bf2f((ushort_t)(u & 0xffffu));
            s1 += al * bf2f((ushort_t)(u >> 16));
        }
        ushort2 o = { f2bf(s0), f2bf(s1) };
        *(ushort2*)(attv + (size_t)b * 512 + tid * 2) = o;
    }
}

// ---------------------------------------------------------------------------
// Persistent encoder scan: 32 blocks, 100 steps, 1 grid-sync per step.
// ---------------------------------------------------------------------------
__global__ __launch_bounds__(256, 1)
void enc_scan(float* ws, const float* __restrict__ enc_bh)
{
    __shared__ __align__(16) char smraw[36864];
    ushort_t (*Alds)[128] = (ushort_t(*)[128])smraw;
    ushort_t (*Blds)[128] = (ushort_t(*)[128])(smraw + 16384);
    const ushort_t* encWhT  = (const ushort_t*)(ws + OFF_ENC_WHT);
    const ushort_t* enc_pre = (const ushort_t*)(ws + OFF_A);
    ushort_t* enc_hs = (ushort_t*)(ws + OFF_ENC_HS);
    float* cenc = ws + OFF_CENC;
    unsigned int* bar = (unsigned int*)(ws + OFF_BAR);
    const int c0 = blockIdx.x * 16;
    float creg[4] = {0.f, 0.f, 0.f, 0.f};

    #pragma unroll 1
    for (int t = 0; t < TENC; ++t) {
        floatx4 acc[5] = {};
        if (t > 0)
            lstm_accum(enc_hs + (size_t)(t - 1) * 32768, encWhT, 512, 0, c0, acc, Alds, Blds);
        lstm_epilogue(acc, enc_bh, nullptr, nullptr,
                      enc_pre + (size_t)t * 163840, creg,
                      (t == TENC - 1) ? cenc : nullptr,
                      enc_hs + (size_t)t * 32768, nullptr, c0);
        gbar(bar, gridDim.x);
    }
}

// ---------------------------------------------------------------------------
// Persistent review scan: 64 blocks (0-31 lstm, 32-63 attend), 8 steps.
// ---------------------------------------------------------------------------
__global__ __launch_bounds__(256, 1)
void rev_scan(float* ws, const float* __restrict__ rev_bh, const float* __restrict__ rev_ba,
              const float* __restrict__ rev_bh2a, const float* __restrict__ rev_Watt)
{
    __shared__ __align__(16) char smraw[36864];
    ushort_t (*Alds)[128] = (ushort_t(*)[128])smraw;
    ushort_t (*Blds)[128] = (ushort_t(*)[128])(smraw + 16384);
    const ushort_t* revWc = (const ushort_t*)(ws + OFF_REVWC);
    const ushort_t* revWh2aT = (const ushort_t*)(ws + OFF_REVWH2AT);
    const ushort_t* rev_proj = (const ushort_t*)(ws + OFF_A);   // [6400][4096]
    const ushort_t* enc_hs = (const ushort_t*)(ws + OFF_ENC_HS);
    ushort_t* thought = (ushort_t*)(ws + OFF_THOUGHT);
    ushort_t* attv = (ushort_t*)(ws + OFF_ATTV);
    ushort_t* hb[2] = { (ushort_t*)(ws + OFF_HB0), (ushort_t*)(ws + OFF_HB1) };
    const float* cenc = ws + OFF_CENC;
    unsigned int* bar = (unsigned int*)(ws + OFF_BAR);
    const int blk = blockIdx.x;
    const int c0 = (blk & 31) * 16;
    const ushort_t* h_enc = enc_hs + (size_t)(TENC - 1) * 32768;

    float creg[4] = {0.f, 0.f, 0.f, 0.f};
    if (blk < 32) {
        const int tid = threadIdx.x, wave = tid >> 6, lane = tid & 63;
        const int m = wave * 16 + (lane >> 4) * 4, c = c0 + (lane & 15);
        #pragma unroll
        for (int rr = 0; rr < 4; ++rr) creg[rr] = cenc[(size_t)(m + rr) * 512 + c];
    }

    const ushort_t* rh = h_enc;
    #pragma unroll 1
    for (int r = 0; r < RSTEPS; ++r) {
        floatx4 acc[5] = {};
        if (blk < 32) {
            lstm_accum(rh, revWc + (size_t)r * 2621440, 1024, 0, c0, acc, Alds, Blds);
        } else {
            attend_fused(rh, rev_proj + (size_t)r * 512, 4096, enc_hs,
                         revWh2aT + (size_t)r * 262144, rev_bh2a + r * 512,
                         rev_Watt + r * 512, attv, TENC, (blk - 32) * 2, smraw);
        }
        gbar(bar, gridDim.x);
        if (blk < 32) {
            lstm_accum(attv, revWc + (size_t)r * 2621440, 1024, 512, c0, acc, Alds, Blds);
            lstm_epilogue(acc, rev_bh + (size_t)r * FIVEL, rev_ba + (size_t)r * FIVEL, nullptr,
                          nullptr, creg, nullptr, hb[r & 1],
                          thought + (size_t)r * 32768, c0);
        }
        gbar(bar, gridDim.x);
        rh = hb[r & 1];
    }
}

// ---------------------------------------------------------------------------
// Persistent decoder scan: 64 blocks (0-31 lstm, 32-63 attend), 50 steps.
// ---------------------------------------------------------------------------
__global__ __launch_bounds__(256, 1)
void dec_scan(float* ws, const float* __restrict__ dec_bi, const float* __restrict__ dec_bh,
              const float* __restrict__ dec_ba, const float* __restrict__ dec_bh2a,
              const float* __restrict__ dec_Watt)
{
    __shared__ __align__(16) char smraw[36864];
    ushort_t (*Alds)[128] = (ushort_t(*)[128])smraw;
    ushort_t (*Blds)[128] = (ushort_t(*)[128])(smraw + 16384);
    const ushort_t* decWc = (const ushort_t*)(ws + OFF_DECWC);
    const ushort_t* decWh2aT = (const ushort_t*)(ws + OFF_DECWH2AT);
    const ushort_t* tproj = (const ushort_t*)(ws + OFF_TPROJ);
    const ushort_t* thought = (const ushort_t*)(ws + OFF_THOUGHT);
    const ushort_t* dec_x = (const ushort_t*)(ws + OFF_DECX);
    const ushort_t* enc_hs = (const ushort_t*)(ws + OFF_ENC_HS);
    ushort_t* dec_h = (ushort_t*)(ws + OFF_DECH);
    ushort_t* attv = (ushort_t*)(ws + OFF_ATTV);
    ushort_t* hb[2] = { (ushort_t*)(ws + OFF_HB0), (ushort_t*)(ws + OFF_HB1) };
    const float* cenc = ws + OFF_CENC;
    unsigned int* bar = (unsigned int*)(ws + OFF_BAR);
    const int blk = blockIdx.x;
    const int c0 = (blk & 31) * 16;
    const ushort_t* h_enc = enc_hs + (size_t)(TENC - 1) * 32768;

    float creg[4] = {0.f, 0.f, 0.f, 0.f};
    if (blk < 32) {
        const int tid = threadIdx.x, wave = tid >> 6, lane = tid & 63;
        const int m = wave * 16 + (lane >> 4) * 4, c = c0 + (lane & 15);
        #pragma unroll
        for (int rr = 0; rr < 4; ++rr) creg[rr] = cenc[(size_t)(m + rr) * 512 + c];
    }

    const ushort_t* dh = h_enc;
    #pragma unroll 1
    for (int t = 0; t < TDEC; ++t) {
        floatx4 acc[5] = {};
        if (blk < 32) {
            lstm_accum(dec_x + (size_t)t * 32768, decWc, 1536, 0, c0, acc, Alds, Blds);
            lstm_accum(dh, decWc, 1536, 512, c0, acc, Alds, Blds);
        } else {
            attend_fused(dh, tproj, 512, thought, decWh2aT, dec_bh2a,
                         dec_Watt, attv, RSTEPS, (blk - 32) * 2, smraw);
        }
        gbar(bar, gridDim.x);
        if (blk < 32) {
            lstm_accum(attv, decWc, 1536, 1024, c0, acc, Alds, Blds);
            lstm_epilogue(acc, dec_bi, dec_bh, dec_ba, nullptr, creg, nullptr,
                          hb[t & 1], dec_h + (size_t)t * 32768, c0);
        }
        gbar(bar, gridDim.x);
        dh = hb[t & 1];
    }
}

// ---------------------------------------------------------------------------
// In-place log-softmax, one contiguous VOUT row per block.
// ---------------------------------------------------------------------------
__global__ __launch_bounds__(256)
void log_softmax_(float* __restrict__ out)
{
    float* row = out + (size_t)blockIdx.x * VOUT;
    const int tid = threadIdx.x;
    float m = -3.0e38f, s = 0.f;
    for (int i = tid; i < VOUT / 4; i += 256) {
        float4 x = ((const float4*)row)[i];
        float xs[4] = {x.x, x.y, x.z, x.w};
        #pragma unroll
        for (int q = 0; q < 4; ++q) {
            float v = xs[q];
            if (v > m) { s = s * __expf(m - v) + 1.0f; m = v; }
            else       { s += __expf(v - m); }
        }
    }
    #pragma unroll
    for (int off = 32; off; off >>= 1) {
        float mo = __shfl_xor(m, off);
        float so = __shfl_xor(s, off);
        float mn = fmaxf(m, mo);
        s = s * __expf(m - mn) + so * __expf(mo - mn);
        m = mn;
    }
    __shared__ float ms[4], ss[4];
    const int wave = tid >> 6, lane = tid & 63;
    if (lane == 0) { ms[wave] = m; ss[wave] = s; }
    __syncthreads();
    float M2 = fmaxf(fmaxf(ms[0], ms[1]), fmaxf(ms[2], ms[3]));
    float S2 = ss[0] * __expf(ms[0] - M2) + ss[1] * __expf(ms[1] - M2) +
               ss[2] * __expf(ms[2] - M2) + ss[3] * __expf(ms[3] - M2);
    float lse = M2 + __logf(S2);
    for (int i = tid; i < VOUT / 4; i += 256) {
        float4 x = ((const float4*)row)[i];
        x.x -= lse; x.y -= lse; x.z -= lse; x.w -= lse;
        ((float4*)row)[i] = x;
    }
}

// ---------------------------------------------------------------------------
extern "C" void kernel_launch(void* const* d_in, const int* in_sizes, int n_in,
                              void* d_out_, int out_size, void* d_ws, size_t ws_size,
                              hipStream_t stream)
{
    const int*   code     = (const int*)  d_in[0];
    const int*   comment  = (const int*)  d_in[1];
    const float* embed    = (const float*)d_in[3];
    const float* enc_Wi   = (const float*)d_in[4];
    const float* enc_bi   = (const float*)d_in[5];
    const float* enc_Wh   = (const float*)d_in[6];
    const float* enc_bh   = (const float*)d_in[7];
    const float* rev_Wh   = (const float*)d_in[8];
    const float* rev_bh   = (const float*)d_in[9];
    const float* rev_Wa   = (const float*)d_in[10];
    const float* rev_ba   = (const float*)d_in[11];
    const float* rev_Wa2a = (const float*)d_in[12];
    const float* rev_ba2a = (const float*)d_in[13];
    const float* rev_Wh2a = (const float*)d_in[14];
    const float* rev_bh2a = (const float*)d_in[15];
    const float* rev_Watt = (const float*)d_in[16];
    const float* dec_Wi   = (const float*)d_in[18];
    const float* dec_bi   = (const float*)d_in[19];
    const float* dec_Wh   = (const float*)d_in[20];
    const float* dec_bh   = (const float*)d_in[21];
    const float* dec_Wa   = (const float*)d_in[22];
    const float* dec_ba   = (const float*)d_in[23];
    const float* dec_Wa2a = (const float*)d_in[24];
    const float* dec_ba2a = (const float*)d_in[25];
    const float* dec_Wh2a = (const float*)d_in[26];
    const float* dec_bh2a = (const float*)d_in[27];
    const float* dec_Watt = (const float*)d_in[28];
    const float* logit_W  = (const float*)d_in[30];
    const float* logit_b  = (const float*)d_in[31];
    float* out = (float*)d_out_;

    float* ws = (float*)d_ws;
    if (ws_size < WS_TOTAL * sizeof(float)) return;

    ushort_t* enc_pre_b   = (ushort_t*)(ws + OFF_A);
    ushort_t* rev_projA   = (ushort_t*)(ws + OFF_A);
    ushort_t* logit_WT    = (ushort_t*)(ws + OFF_LOGWT);
    ushort_t* dec_h_b     = (ushort_t*)(ws + OFF_DECH);
    ushort_t* WiT_enc     = (ushort_t*)(ws + OFF_WIT_ENC);
    ushort_t* enc_x_b     = (ushort_t*)(ws + OFF_ENCX);
    ushort_t* enc_hs_b    = (ushort_t*)(ws + OFF_ENC_HS);
    ushort_t* encWhT      = (ushort_t*)(ws + OFF_ENC_WHT);
    ushort_t* revWcomb    = (ushort_t*)(ws + OFF_REVWC);
    ushort_t* decWcomb    = (ushort_t*)(ws + OFF_DECWC);
    ushort_t* revWT       = (ushort_t*)(ws + OFF_REVWT);
    ushort_t* decWT       = (ushort_t*)(ws + OFF_DECWT);
    ushort_t* revWh2aT    = (ushort_t*)(ws + OFF_REVWH2AT);
    ushort_t* decWh2aT    = (ushort_t*)(ws + OFF_DECWH2AT);
    ushort_t* dec_x_b     = (ushort_t*)(ws + OFF_DECX);
    ushort_t* thought_b   = (ushort_t*)(ws + OFF_THOUGHT);
    ushort_t* tproj_b     = (ushort_t*)(ws + OFF_TPROJ);

    const dim3 blk(256);

    // barrier state must start at {0,0} every call
    hipMemsetAsync((char*)d_ws + OFF_BAR * sizeof(float), 0, 8, stream);

    // ---- prep: gathers + weight transposes (fp32 -> bf16 [N][K]) ----
    gather_embed<<<TENC * BB, 128, 0, stream>>>(embed, code, TENC, enc_x_b);
    gather_embed<<<TDEC * BB, 128, 0, stream>>>(embed, comment, TDEC, dec_x_b);
    conv_transpose<<<dim3(80, 16, 1), blk, 0, stream>>>(enc_Wi, WiT_enc, FIVEL, 512, 0, 0, 0);
    conv_transpose<<<dim3(80, 16, 1), blk, 0, stream>>>(enc_Wh, encWhT, FIVEL, 512, 0, 0, 0);
    conv_transpose<<<dim3(80, 16, 8), blk, 0, stream>>>(rev_Wh, revWcomb, FIVEL, 1024, 0,    1310720, 2621440);
    conv_transpose<<<dim3(80, 16, 8), blk, 0, stream>>>(rev_Wa, revWcomb, FIVEL, 1024, 512,  1310720, 2621440);
    conv_transpose<<<dim3(16, 16, 8), blk, 0, stream>>>(rev_Wa2a, revWT, 512, 512, 0,        262144, 262144);
    conv_transpose<<<dim3(16, 16, 8), blk, 0, stream>>>(rev_Wh2a, revWh2aT, 512, 512, 0,     262144, 262144);
    conv_transpose<<<dim3(80, 16, 1), blk, 0, stream>>>(dec_Wi, decWcomb, FIVEL, 1536, 0, 0, 0);
    conv_transpose<<<dim3(80, 16, 1), blk, 0, stream>>>(dec_Wh, decWcomb, FIVEL, 1536, 512, 0, 0);
    conv_transpose<<<dim3(80, 16, 1), blk, 0, stream>>>(dec_Wa, decWcomb, FIVEL, 1536, 1024, 0, 0);
    conv_transpose<<<dim3(16, 16, 1), blk, 0, stream>>>(dec_Wa2a, decWT, 512, 512, 0, 0, 0);
    conv_transpose<<<dim3(16, 16, 1), blk, 0, stream>>>(dec_Wh2a, decWh2aT, 512, 512, 0, 0, 0);

    // ---- hoisted encoder input GEMM: enc_pre = enc_x @ Wi + bi ----
    gemm_bf16<<<dim3(FIVEL / 128, TENC * BB / 128), blk, 0, stream>>>(
        enc_x_b, WiT_enc, enc_bi, nullptr, enc_pre_b, FIVEL, EE, FIVEL, 0);

    // ---- persistent encoder scan (100 steps, 32 blocks) ----
    enc_scan<<<32, blk, 0, stream>>>(ws, enc_bh);

    // ---- hoisted review projections: rev_proj_all[m][r*512+n] (M=6400,N=4096) ----
    gemm_bf16<<<dim3(32, 50), blk, 0, stream>>>(
        enc_hs_b, revWT, rev_ba2a, nullptr, rev_projA, 4096, LDIM, 4096, 0);

    // ---- persistent review scan (8 steps, 64 blocks) ----
    rev_scan<<<64, blk, 0, stream>>>(ws, rev_bh, rev_ba, rev_bh2a, rev_Watt);

    // ---- thought projection + logit_W transpose (rev_proj_all now dead) ----
    gemm_bf16<<<dim3(4, 4), blk, 0, stream>>>(
        thought_b, decWT, dec_ba2a, nullptr, tproj_b, HDIM, LDIM, HDIM, 0);
    conv_transpose<<<dim3((VOUT + 31) / 32, 16, 1), blk, 0, stream>>>(
        logit_W, logit_WT, VOUT, 512, 0, 0, 0);

    // ---- persistent decoder scan (50 steps, 64 blocks) ----
    dec_scan<<<64, blk, 0, stream>>>(ws, dec_bi, dec_bh, dec_ba, dec_bh2a, dec_Watt);

    // ---- one big logit GEMM (remapped rows) + log-softmax ----
    gemm_bf16<<<dim3((VOUT + 127) / 128, TDEC * BB / 128), blk, 0, stream>>>(
        dec_h_b, logit_WT, logit_b, out, nullptr, VOUT, LDIM, VOUT, 1);
    log_softmax_<<<TDEC * BB, blk, 0, stream>>>(out);
}

// Round 5
// 4592.356 us; speedup vs baseline: 1.2846x; 1.2846x over previous
//
#include <hip/hip_runtime.h>
#include <math.h>
#include <stdint.h>

#define BB     64
#define TENC   100
#define TDEC   50
#define LDIM   512
#define EE     512
#define HDIM   512
#define FIVEL  2560
#define RSTEPS 8
#define VOUT   30000

typedef __attribute__((ext_vector_type(8))) short short8v;   // 8 x bf16
typedef __attribute__((ext_vector_type(4))) float floatx4;
typedef unsigned short ushort_t;

// ---------------- workspace offsets (float units) ----------------
// Region A (13,107,200 fl), time-multiplexed:
//   prep/enc:   enc_pre_b [0..8,192,000) + WiT_enc + enc_x_b
//   review:     rev_projA [0..13,107,200)   (6400 x 4096 bf16)
//   post-rev:   logit_WT [0..7,680,000) + dec_h_b + dec_pre_b
static const size_t OFF_A        = 0;
static const size_t OFF_WIT_ENC  = 8192000;
static const size_t OFF_ENCX     = 8847360;    // ends 10,485,760
static const size_t OFF_LOGWT    = 0;
static const size_t OFF_DECH     = 7680000;    // ends 8,499,200
static const size_t OFF_DECPRE   = 8499200;    // ends 12,595,200
static const size_t OFF_ENC_HS   = 13107200;   // 1,638,400
static const size_t OFF_ENC_WHT  = 14745600;   // 655,360
static const size_t OFF_REVWC    = 15400960;   // 10,485,760 (8 x 2560 x 1024 bf16)
static const size_t OFF_DECWC    = 25886720;   // 1,310,720  (2560 x 1024 bf16)
static const size_t OFF_WIT_DEC  = 27197440;   // 655,360
static const size_t OFF_REVWT    = 27852800;   // 1,048,576
static const size_t OFF_DECWT    = 28901376;   // 131,072
static const size_t OFF_REVWH2AT = 29032448;   // 1,048,576
static const size_t OFF_DECWH2AT = 30081024;   // 131,072
static const size_t OFF_DECX     = 30212096;   // 819,200
static const size_t OFF_THOUGHT  = 31031296;   // 131,072
static const size_t OFF_TPROJ    = 31162368;   // 131,072
static const size_t OFF_HB0      = 31293440;   // 16,384
static const size_t OFF_HB1      = 31309824;   // 16,384
static const size_t OFF_ATTV     = 31326208;   // 16,384
static const size_t OFF_H0       = 31342592;   // 16,384
static const size_t OFF_C0       = 31358976;   // 4 x 32,768
static const size_t WS_TOTAL     = 31490048;   // 125.96 MB

__device__ __forceinline__ float sigmoidf_(float x) { return 1.0f / (1.0f + __expf(-x)); }
__device__ __forceinline__ float tanh_fast(float x) { return 1.0f - 2.0f / (__expf(2.0f * x) + 1.0f); }
__device__ __forceinline__ unsigned short f2bf(float x) {
    unsigned u = __float_as_uint(x);
    u += 0x7FFFu + ((u >> 16) & 1u);
    return (unsigned short)(u >> 16);
}
__device__ __forceinline__ float bf2f(unsigned short h) {
    return __uint_as_float(((unsigned)h) << 16);
}

// ---------------------------------------------------------------------------
// Gather embedding rows -> bf16 matrix X[m][E], m = t*BB + b.
// ---------------------------------------------------------------------------
__global__ __launch_bounds__(128)
void gather_embed(const float* __restrict__ embed, const int* __restrict__ tok,
                  int T, ushort_t* __restrict__ X)
{
    int m = blockIdx.x, t = m / BB, b = m % BB;
    const float* src = embed + (size_t)tok[b * T + t] * EE;
    float4 v = *(const float4*)(src + threadIdx.x * 4);
    ushort4 o = { f2bf(v.x), f2bf(v.y), f2bf(v.z), f2bf(v.w) };
    *(ushort4*)(X + (size_t)m * EE + threadIdx.x * 4) = o;
}

// ---------------------------------------------------------------------------
// WT[z][n][kofs+k] = bf16(W[z][k][n]).  W rows K=gridDim.y*32, cols N.
// ---------------------------------------------------------------------------
__global__ __launch_bounds__(256)
void conv_transpose(const float* __restrict__ W, ushort_t* __restrict__ WT,
                    int N, int ldWT, int kofs, long Wz, long WTz)
{
    W  += (size_t)blockIdx.z * Wz;
    WT += (size_t)blockIdx.z * WTz;
    __shared__ float tile[32][33];
    int n0 = blockIdx.x * 32, k0 = blockIdx.y * 32;
    int tx = threadIdx.x & 31, ty = threadIdx.x >> 5;
    #pragma unroll
    for (int i = 0; i < 4; ++i) {
        int k = k0 + ty + i * 8, n = n0 + tx;
        tile[ty + i * 8][tx] = (n < N) ? W[(size_t)k * N + n] : 0.f;
    }
    __syncthreads();
    #pragma unroll
    for (int i = 0; i < 4; ++i) {
        int n = n0 + ty + i * 8, k = k0 + tx;
        if (n < N) WT[(size_t)n * ldWT + kofs + k] = f2bf(tile[tx][ty + i * 8]);
    }
}

// ---------------------------------------------------------------------------
// bf16 MFMA GEMM (R2/R3-proven): C[m][n] = sum_k A[m][k]*BT[n][k] + bias[n]
// ---------------------------------------------------------------------------
__global__ __launch_bounds__(256)
void gemm_bf16(const ushort_t* __restrict__ A, const ushort_t* __restrict__ BT,
               const float* __restrict__ bias, float* __restrict__ C,
               ushort_t* __restrict__ Cb, int N, int K, long ldc, int remap)
{
    __shared__ ushort_t lds[2][128][32];
    const int tid  = threadIdx.x;
    const int wave = tid >> 6, lane = tid & 63;
    const int m0 = blockIdx.y * 128, n0 = blockIdx.x * 128;
    const int wr = wave >> 1, wc = wave & 1;

    floatx4 acc[4][4] = {};
    const int sr  = lane >> 2;
    const int scp = lane & 3;

    for (int k0 = 0; k0 < K; k0 += 32) {
        #pragma unroll
        for (int half = 0; half < 2; ++half) {
            int rbase = wave * 32 + half * 16;
            int r = rbase + sr;
            int c = scp ^ ((r >> 1) & 3);
            const ushort_t* ga = A + (size_t)(m0 + r) * K + k0 + c * 8;
            int nr = n0 + r; if (nr >= N) nr = 0;
            const ushort_t* gb = BT + (size_t)nr * K + k0 + c * 8;
            __builtin_amdgcn_global_load_lds(
                (const __attribute__((address_space(1))) void*)ga,
                (__attribute__((address_space(3))) void*)&lds[0][rbase][0], 16, 0, 0);
            __builtin_amdgcn_global_load_lds(
                (const __attribute__((address_space(1))) void*)gb,
                (__attribute__((address_space(3))) void*)&lds[1][rbase][0], 16, 0, 0);
        }
        __syncthreads();

        short8v af[4], bv[4];
        #pragma unroll
        for (int i = 0; i < 4; ++i) {
            int ra = wr * 64 + i * 16 + (lane & 15);
            int ca = (lane >> 4) ^ ((ra >> 1) & 3);
            af[i] = *(const short8v*)&lds[0][ra][ca * 8];
            int rb = wc * 64 + i * 16 + (lane & 15);
            int cb = (lane >> 4) ^ ((rb >> 1) & 3);
            bv[i] = *(const short8v*)&lds[1][rb][cb * 8];
        }
        #pragma unroll
        for (int i = 0; i < 4; ++i)
            #pragma unroll
            for (int j = 0; j < 4; ++j)
                acc[i][j] = __builtin_amdgcn_mfma_f32_16x16x32_bf16(af[i], bv[j], acc[i][j], 0, 0, 0);
        __syncthreads();
    }

    const int crow0 = m0 + wr * 64 + (lane >> 4) * 4;
    const int ccol0 = n0 + wc * 64 + (lane & 15);
    #pragma unroll
    for (int i = 0; i < 4; ++i) {
        #pragma unroll
        for (int j = 0; j < 4; ++j) {
            int col = ccol0 + j * 16;
            if (col < N) {
                float bval = bias ? bias[col] : 0.f;
                #pragma unroll
                for (int rr = 0; rr < 4; ++rr) {
                    int m = crow0 + i * 16 + rr;
                    long orow = m;
                    if (remap) { int t = m >> 6, b = m & 63; orow = (long)b * TDEC + t; }
                    float v = acc[i][j][rr] + bval;
                    if (Cb) Cb[orow * ldc + col] = f2bf(v);
                    else    C [orow * ldc + col] = v;
                }
            }
        }
    }
}

// ---------------------------------------------------------------------------
// Small-M (=64) MFMA LSTM step (R3-proven). 32 blocks x 256 thr; block covers
// a 16-col tile c0 and all 5 gate slices. Fused maxout-LSTM epilogue.
// ---------------------------------------------------------------------------
__global__ __launch_bounds__(256)
void lstm_small(const ushort_t* __restrict__ a0,
                const ushort_t* __restrict__ a1,
                const ushort_t* __restrict__ BT, int ldBT,
                const ushort_t* __restrict__ pre,
                const float* __restrict__ b0, const float* __restrict__ b1,
                const float* __restrict__ c_in, float* __restrict__ c_out,
                ushort_t* __restrict__ h_out, ushort_t* __restrict__ h_copy)
{
    __shared__ ushort_t Alds[64][128];     // 16 KB
    __shared__ ushort_t Blds[80][128];     // 20 KB
    const int tid = threadIdx.x;
    const int wave = tid >> 6, lane = tid & 63;
    const int c0 = blockIdx.x * 16;

    const ushort_t* segs[2] = {a0, a1};
    const int nseg = a1 ? 2 : 1;
    const int NO = nseg * 4;

    floatx4 acc[5] = {};
    short8v ra[4], rb[5];

    #define LOAD_TILE(ot_) do {                                                \
        int seg_ = (ot_) >> 2, k0_ = ((ot_) & 3) * 128;                        \
        const ushort_t* A_ = segs[seg_];                                       \
        _Pragma("unroll")                                                      \
        for (int j = 0; j < 4; ++j) {                                          \
            int idx = tid + j * 256; int r = idx >> 4, ch = idx & 15;          \
            ra[j] = *(const short8v*)(A_ + (size_t)r * 512 + k0_ + ch * 8);    \
        }                                                                      \
        _Pragma("unroll")                                                      \
        for (int j = 0; j < 5; ++j) {                                          \
            int idx = tid + j * 256; int r = idx >> 4, ch = idx & 15;          \
            int grow = (r >> 4) * 512 + c0 + (r & 15);                         \
            rb[j] = *(const short8v*)(BT + (size_t)grow * ldBT + seg_ * 512 + k0_ + ch * 8); \
        }                                                                      \
    } while (0)

    LOAD_TILE(0);
    for (int ot = 0; ot < NO; ++ot) {
        __syncthreads();
        #pragma unroll
        for (int j = 0; j < 4; ++j) {
            int idx = tid + j * 256; int r = idx >> 4, ch = idx & 15;
            *(short8v*)&Alds[r][(ch ^ (r & 7)) * 8] = ra[j];
        }
        #pragma unroll
        for (int j = 0; j < 5; ++j) {
            int idx = tid + j * 256; int r = idx >> 4, ch = idx & 15;
            *(short8v*)&Blds[r][(ch ^ (r & 7)) * 8] = rb[j];
        }
        __syncthreads();
        if (ot + 1 < NO) LOAD_TILE(ot + 1);

        const int arow = wave * 16 + (lane & 15);
        const int q = lane >> 4;
        #pragma unroll
        for (int kk = 0; kk < 4; ++kk) {
            int ch = kk * 4 + q;
            short8v af = *(const short8v*)&Alds[arow][(ch ^ (arow & 7)) * 8];
            #pragma unroll
            for (int g = 0; g < 5; ++g) {
                int brow = g * 16 + (lane & 15);
                short8v bf = *(const short8v*)&Blds[brow][(ch ^ (brow & 7)) * 8];
                acc[g] = __builtin_amdgcn_mfma_f32_16x16x32_bf16(af, bf, acc[g], 0, 0, 0);
            }
        }
    }
    #undef LOAD_TILE

    const int m = wave * 16 + (lane >> 4) * 4;
    const int c = c0 + (lane & 15);
    float bias[5];
    #pragma unroll
    for (int g = 0; g < 5; ++g) {
        float v = b0[g * 512 + c];
        if (b1) v += b1[g * 512 + c];
        bias[g] = v;
    }
    #pragma unroll
    for (int rr = 0; rr < 4; ++rr) {
        int row = m + rr;
        float s[5];
        #pragma unroll
        for (int g = 0; g < 5; ++g) {
            s[g] = acc[g][rr] + bias[g];
            if (pre) s[g] += bf2f(pre[(size_t)row * FIVEL + g * 512 + c]);
        }
        float ig = sigmoidf_(s[0]), fg = sigmoidf_(s[1]), og = sigmoidf_(s[2]);
        float tt = fmaxf(s[3], s[4]);
        float c2 = fg * c_in[(size_t)row * 512 + c] + ig * tt;
        float h2 = og * tanh_fast(c2);
        c_out[(size_t)row * 512 + c] = c2;
        ushort_t hb_ = f2bf(h2);
        h_out[(size_t)row * 512 + c] = hb_;
        if (h_copy) h_copy[(size_t)row * 512 + c] = hb_;
    }
}

// ---------------------------------------------------------------------------
// Fused hproj + attention (R4-proven math), standalone kernel.
// 32 blocks x 2 batches. hproj[b,n] = b2a[n] + sum_k h[b,k]*W2aT[n,k];
// e = sum tanh(proj+hp)*Watt; softmax over A; attv[b] = sum_a alpha*feats.
// ---------------------------------------------------------------------------
__global__ __launch_bounds__(256)
void attfuse(const ushort_t* __restrict__ hprev,
             const ushort_t* __restrict__ projBase, long projLd,
             const ushort_t* __restrict__ feats,
             const ushort_t* __restrict__ W2aT, const float* __restrict__ b2a,
             const float* __restrict__ Watt, ushort_t* __restrict__ attv,
             int A)
{
    __shared__ ushort_t hl[2][512];
    __shared__ float hp[2][512];
    __shared__ float wa[512];
    __shared__ float ealpha[2][128];
    const int b0 = blockIdx.x * 2;
    const int tid = threadIdx.x;
    {
        int i4 = tid * 4;
        int bi = i4 >> 9, k = i4 & 511;
        *(ushort4*)&hl[bi][k] = *(const ushort4*)(hprev + (size_t)(b0 + bi) * 512 + k);
        wa[tid] = Watt[tid];
        wa[tid + 256] = Watt[tid + 256];
    }
    __syncthreads();
    #pragma unroll
    for (int half = 0; half < 2; ++half) {
        int n = tid + half * 256;
        float a0 = b2a[n], a1 = a0;
        const ushort_t* wrow = W2aT + (size_t)n * 512;
        #pragma unroll 4
        for (int k8 = 0; k8 < 64; ++k8) {
            short8v w  = *(const short8v*)(wrow + k8 * 8);
            short8v h0 = *(const short8v*)&hl[0][k8 * 8];
            short8v h1 = *(const short8v*)&hl[1][k8 * 8];
            #pragma unroll
            for (int e = 0; e < 8; ++e) {
                float wf = bf2f((ushort_t)w[e]);
                a0 += wf * bf2f((ushort_t)h0[e]);
                a1 += wf * bf2f((ushort_t)h1[e]);
            }
        }
        hp[0][n] = a0;
        hp[1][n] = a1;
    }
    __syncthreads();
    const int wave = tid >> 6, lane = tid & 63;
    for (int idx = wave; idx < 2 * A; idx += 4) {
        int a = idx >> 1, bi = idx & 1;
        short8v pv = *(const short8v*)(projBase + ((size_t)a * 64 + b0 + bi) * projLd + lane * 8);
        float e = 0.f;
        #pragma unroll
        for (int j = 0; j < 8; ++j) {
            int h = lane * 8 + j;
            e += tanh_fast(bf2f((ushort_t)pv[j]) + hp[bi][h]) * wa[h];
        }
        #pragma unroll
        for (int off = 32; off; off >>= 1) e += __shfl_xor(e, off);
        if (lane == 0) ealpha[bi][a] = e;
    }
    __syncthreads();
    if (wave < 2) {
        int bi = wave;
        float v1 = (lane < A) ? ealpha[bi][lane] : -3.0e38f;
        float v2 = (lane + 64 < A) ? ealpha[bi][lane + 64] : -3.0e38f;
        float mm = fmaxf(v1, v2);
        #pragma unroll
        for (int off = 32; off; off >>= 1) mm = fmaxf(mm, __shfl_xor(mm, off));
        float x1 = (lane < A) ? __expf(v1 - mm) : 0.f;
        float x2 = (lane + 64 < A) ? __expf(v2 - mm) : 0.f;
        float ss = x1 + x2;
        #pragma unroll
        for (int off = 32; off; off >>= 1) ss += __shfl_xor(ss, off);
        float inv = 1.f / ss;
        if (lane < A) ealpha[bi][lane] = x1 * inv;
        if (lane + 64 < A) ealpha[bi][lane + 64] = x2 * inv;
    }
    __syncthreads();
    #pragma unroll
    for (int bi = 0; bi < 2; ++bi) {
        int b = b0 + bi;
        float s0 = 0.f, s1 = 0.f;
        for (int a = 0; a < A; ++a) {
            float al = ealpha[bi][a];
            unsigned int u = *(const unsigned int*)(feats + ((size_t)a * 64 + b) * 512 + tid * 2);
            s0 += al * bf2f((ushort_t)(u & 0xffffu));
            s1 += al * bf2f((ushort_t)(u >> 16));
        }
        ushort2 o = { f2bf(s0), f2bf(s1) };
        *(ushort2*)(attv + (size_t)b * 512 + tid * 2) = o;
    }
}

// ---------------------------------------------------------------------------
// In-place log-softmax, one contiguous VOUT row per block.
// ---------------------------------------------------------------------------
__global__ __launch_bounds__(256)
void log_softmax_(float* __restrict__ out)
{
    float* row = out + (size_t)blockIdx.x * VOUT;
    const int tid = threadIdx.x;
    float m = -3.0e38f, s = 0.f;
    for (int i = tid; i < VOUT / 4; i += 256) {
        float4 x = ((const float4*)row)[i];
        float xs[4] = {x.x, x.y, x.z, x.w};
        #pragma unroll
        for (int q = 0; q < 4; ++q) {
            float v = xs[q];
            if (v > m) { s = s * __expf(m - v) + 1.0f; m = v; }
            else       { s += __expf(v - m); }
        }
    }
    #pragma unroll
    for (int off = 32; off; off >>= 1) {
        float mo = __shfl_xor(m, off);
        float so = __shfl_xor(s, off);
        float mn = fmaxf(m, mo);
        s = s * __expf(m - mn) + so * __expf(mo - mn);
        m = mn;
    }
    __shared__ float ms[4], ss[4];
    const int wave = tid >> 6, lane = tid & 63;
    if (lane == 0) { ms[wave] = m; ss[wave] = s; }
    __syncthreads();
    float M2 = fmaxf(fmaxf(ms[0], ms[1]), fmaxf(ms[2], ms[3]));
    float S2 = ss[0] * __expf(ms[0] - M2) + ss[1] * __expf(ms[1] - M2) +
               ss[2] * __expf(ms[2] - M2) + ss[3] * __expf(ms[3] - M2);
    float lse = M2 + __logf(S2);
    for (int i = tid; i < VOUT / 4; i += 256) {
        float4 x = ((const float4*)row)[i];
        x.x -= lse; x.y -= lse; x.z -= lse; x.w -= lse;
        ((float4*)row)[i] = x;
    }
}

// ---------------------------------------------------------------------------
extern "C" void kernel_launch(void* const* d_in, const int* in_sizes, int n_in,
                              void* d_out_, int out_size, void* d_ws, size_t ws_size,
                              hipStream_t stream)
{
    const int*   code     = (const int*)  d_in[0];
    const int*   comment  = (const int*)  d_in[1];
    const float* embed    = (const float*)d_in[3];
    const float* enc_Wi   = (const float*)d_in[4];
    const float* enc_bi   = (const float*)d_in[5];
    const float* enc_Wh   = (const float*)d_in[6];
    const float* enc_bh   = (const float*)d_in[7];
    const float* rev_Wh   = (const float*)d_in[8];
    const float* rev_bh   = (const float*)d_in[9];
    const float* rev_Wa   = (const float*)d_in[10];
    const float* rev_ba   = (const float*)d_in[11];
    const float* rev_Wa2a = (const float*)d_in[12];
    const float* rev_ba2a = (const float*)d_in[13];
    const float* rev_Wh2a = (const float*)d_in[14];
    const float* rev_bh2a = (const float*)d_in[15];
    const float* rev_Watt = (const float*)d_in[16];
    const float* dec_Wi   = (const float*)d_in[18];
    const float* dec_bi   = (const float*)d_in[19];
    const float* dec_Wh   = (const float*)d_in[20];
    const float* dec_bh   = (const float*)d_in[21];
    const float* dec_Wa   = (const float*)d_in[22];
    const float* dec_ba   = (const float*)d_in[23];
    const float* dec_Wa2a = (const float*)d_in[24];
    const float* dec_ba2a = (const float*)d_in[25];
    const float* dec_Wh2a = (const float*)d_in[26];
    const float* dec_bh2a = (const float*)d_in[27];
    const float* dec_Watt = (const float*)d_in[28];
    const float* logit_W  = (const float*)d_in[30];
    const float* logit_b  = (const float*)d_in[31];
    float* out = (float*)d_out_;

    float* ws = (float*)d_ws;
    if (ws_size < WS_TOTAL * sizeof(float)) return;

    ushort_t* enc_pre_b = (ushort_t*)(ws + OFF_A);
    ushort_t* rev_projA = (ushort_t*)(ws + OFF_A);
    ushort_t* logit_WT  = (ushort_t*)(ws + OFF_LOGWT);
    ushort_t* dec_h_b   = (ushort_t*)(ws + OFF_DECH);
    ushort_t* dec_pre_b = (ushort_t*)(ws + OFF_DECPRE);
    ushort_t* WiT_enc   = (ushort_t*)(ws + OFF_WIT_ENC);
    ushort_t* enc_x_b   = (ushort_t*)(ws + OFF_ENCX);
    ushort_t* enc_hs_b  = (ushort_t*)(ws + OFF_ENC_HS);
    ushort_t* encWhT    = (ushort_t*)(ws + OFF_ENC_WHT);
    ushort_t* revWcomb  = (ushort_t*)(ws + OFF_REVWC);
    ushort_t* decWcomb  = (ushort_t*)(ws + OFF_DECWC);
    ushort_t* WiT_dec   = (ushort_t*)(ws + OFF_WIT_DEC);
    ushort_t* revWT     = (ushort_t*)(ws + OFF_REVWT);
    ushort_t* decWT     = (ushort_t*)(ws + OFF_DECWT);
    ushort_t* revWh2aT  = (ushort_t*)(ws + OFF_REVWH2AT);
    ushort_t* decWh2aT  = (ushort_t*)(ws + OFF_DECWH2AT);
    ushort_t* dec_x_b   = (ushort_t*)(ws + OFF_DECX);
    ushort_t* thought_b = (ushort_t*)(ws + OFF_THOUGHT);
    ushort_t* tproj_b   = (ushort_t*)(ws + OFF_TPROJ);
    ushort_t* hb[2] = { (ushort_t*)(ws + OFF_HB0), (ushort_t*)(ws + OFF_HB1) };
    ushort_t* attv_b    = (ushort_t*)(ws + OFF_ATTV);
    ushort_t* h0_b      = (ushort_t*)(ws + OFF_H0);
    float* cbuf[4];
    for (int i = 0; i < 4; ++i) cbuf[i] = ws + OFF_C0 + (size_t)i * 32768;

    const dim3 blk(256);

    hipMemsetAsync(cbuf[0], 0, (size_t)BB * LDIM * sizeof(float), stream);
    hipMemsetAsync(h0_b, 0, (size_t)BB * LDIM * sizeof(ushort_t), stream);

    // ---- prep: gathers + weight transposes (fp32 -> bf16 [N][K]) ----
    gather_embed<<<TENC * BB, 128, 0, stream>>>(embed, code, TENC, enc_x_b);
    gather_embed<<<TDEC * BB, 128, 0, stream>>>(embed, comment, TDEC, dec_x_b);
    conv_transpose<<<dim3(80, 16, 1), blk, 0, stream>>>(enc_Wi, WiT_enc, FIVEL, 512, 0, 0, 0);
    conv_transpose<<<dim3(80, 16, 1), blk, 0, stream>>>(enc_Wh, encWhT, FIVEL, 512, 0, 0, 0);
    conv_transpose<<<dim3(80, 16, 8), blk, 0, stream>>>(rev_Wh, revWcomb, FIVEL, 1024, 0,   1310720, 2621440);
    conv_transpose<<<dim3(80, 16, 8), blk, 0, stream>>>(rev_Wa, revWcomb, FIVEL, 1024, 512, 1310720, 2621440);
    conv_transpose<<<dim3(16, 16, 8), blk, 0, stream>>>(rev_Wa2a, revWT, 512, 512, 0,       262144, 262144);
    conv_transpose<<<dim3(16, 16, 8), blk, 0, stream>>>(rev_Wh2a, revWh2aT, 512, 512, 0,    262144, 262144);
    conv_transpose<<<dim3(80, 16, 1), blk, 0, stream>>>(dec_Wi, WiT_dec, FIVEL, 512, 0, 0, 0);
    conv_transpose<<<dim3(80, 16, 1), blk, 0, stream>>>(dec_Wh, decWcomb, FIVEL, 1024, 0, 0, 0);
    conv_transpose<<<dim3(80, 16, 1), blk, 0, stream>>>(dec_Wa, decWcomb, FIVEL, 1024, 512, 0, 0);
    conv_transpose<<<dim3(16, 16, 1), blk, 0, stream>>>(dec_Wa2a, decWT, 512, 512, 0, 0, 0);
    conv_transpose<<<dim3(16, 16, 1), blk, 0, stream>>>(dec_Wh2a, decWh2aT, 512, 512, 0, 0, 0);

    // ---- hoisted encoder input GEMM: enc_pre = enc_x @ Wi + bi ----
    gemm_bf16<<<dim3(FIVEL / 128, TENC * BB / 128), blk, 0, stream>>>(
        enc_x_b, WiT_enc, enc_bi, nullptr, enc_pre_b, FIVEL, EE, FIVEL, 0);

    // ---- encoder scan (per-step kernels; h lives in enc_hs_b slots) ----
    for (int t = 0; t < TENC; ++t) {
        const ushort_t* hin = (t == 0) ? h0_b : enc_hs_b + (size_t)(t - 1) * 32768;
        lstm_small<<<32, blk, 0, stream>>>(
            hin, nullptr, encWhT, 512,
            enc_pre_b + (size_t)t * 163840,
            enc_bh, nullptr,
            cbuf[t & 1], cbuf[(t + 1) & 1],
            enc_hs_b + (size_t)t * 32768, nullptr);
    }
    const ushort_t* h_enc = enc_hs_b + (size_t)(TENC - 1) * 32768;
    // c_enc = cbuf[0] (TENC = 100 even)

    // ---- hoisted review projections: rev_projA[m][r*512+n] ----
    gemm_bf16<<<dim3(32, 50), blk, 0, stream>>>(
        enc_hs_b, revWT, rev_ba2a, nullptr, rev_projA, 4096, LDIM, 4096, 0);

    // ---- review scan ----
    const ushort_t* rh = h_enc;
    for (int r = 0; r < RSTEPS; ++r) {
        attfuse<<<32, blk, 0, stream>>>(
            rh, rev_projA + (size_t)r * 512, 4096, enc_hs_b,
            revWh2aT + (size_t)r * 262144, rev_bh2a + (size_t)r * 512,
            rev_Watt + (size_t)r * 512, attv_b, TENC);
        const float* ci = (r == 0) ? cbuf[0] : cbuf[2 + ((r - 1) & 1)];
        lstm_small<<<32, blk, 0, stream>>>(
            rh, attv_b, revWcomb + (size_t)r * 2621440, 1024,
            nullptr, rev_bh + (size_t)r * FIVEL, rev_ba + (size_t)r * FIVEL,
            ci, cbuf[2 + (r & 1)],
            hb[r & 1], thought_b + (size_t)r * 32768);
        rh = hb[r & 1];
    }

    // ---- tproj + logit_WT + dec_pre (region A: rev_projA now dead) ----
    gemm_bf16<<<dim3(4, 4), blk, 0, stream>>>(
        thought_b, decWT, dec_ba2a, nullptr, tproj_b, HDIM, LDIM, HDIM, 0);
    conv_transpose<<<dim3((VOUT + 31) / 32, 16, 1), blk, 0, stream>>>(
        logit_W, logit_WT, VOUT, 512, 0, 0, 0);
    gemm_bf16<<<dim3(FIVEL / 128, TDEC * BB / 128), blk, 0, stream>>>(
        dec_x_b, WiT_dec, dec_bi, nullptr, dec_pre_b, FIVEL, EE, FIVEL, 0);

    // ---- decoder scan ----
    const ushort_t* dh = h_enc;
    for (int t = 0; t < TDEC; ++t) {
        attfuse<<<32, blk, 0, stream>>>(
            dh, tproj_b, 512, thought_b,
            decWh2aT, dec_bh2a, dec_Watt, attv_b, RSTEPS);
        const float* ci = (t == 0) ? cbuf[0] : cbuf[2 + ((t - 1) & 1)];
        lstm_small<<<32, blk, 0, stream>>>(
            dh, attv_b, decWcomb, 1024,
            dec_pre_b + (size_t)t * 163840,
            dec_bh, dec_ba,
            ci, cbuf[2 + (t & 1)],
            hb[t & 1], dec_h_b + (size_t)t * 32768);
        dh = hb[t & 1];
    }

    // ---- one big logit GEMM (remapped rows) + log-softmax ----
    gemm_bf16<<<dim3((VOUT + 127) / 128, TDEC * BB / 128), blk, 0, stream>>>(
        dec_h_b, logit_WT, logit_b, out, nullptr, VOUT, LDIM, VOUT, 1);
    log_softmax_<<<TDEC * BB, blk, 0, stream>>>(out);
}